// Round 2
// baseline (251.674 us; speedup 1.0000x reference)
//
#include <hip/hip_runtime.h>

#define N_NODES 100000
#define NUM_SAMPLE 25
#define VOCAB 500000
#define FEAT_DIM 128
#define SPLIT (VOCAB / 2)

// Two vocab-chunked passes. Each pass touches only a 128 MB slice of the
// feature table so repeat gathers hit the 256 MB Infinity Cache instead of
// thrashing it. Pass 0 writes partial sums; pass 1 adds its partial and
// divides by NUM_SAMPLE. Stream order serializes the passes.
template <int PASS>
__global__ __launch_bounds__(256) void agg_pass(
    const float* __restrict__ feat,
    const int* __restrict__ idx,
    float* __restrict__ out)
{
    const int gid  = blockIdx.x * blockDim.x + threadIdx.x;
    const int node = gid >> 5;           // 32 lanes per node
    const int lane = gid & 31;
    if (node >= N_NODES) return;

    const int* __restrict__ row_idx = idx + node * NUM_SAMPLE;

    float4 acc = make_float4(0.f, 0.f, 0.f, 0.f);

    #pragma unroll 5
    for (int s = 0; s < NUM_SAMPLE; ++s) {
        const int r = row_idx[s];
        const bool in_chunk = (PASS == 0) ? (r < SPLIT) : (r >= SPLIT);
        if (in_chunk) {   // uniform across the 32-lane group -> cheap branch
            float4 v = reinterpret_cast<const float4*>(
                           feat + (size_t)r * FEAT_DIM)[lane];
            acc.x += v.x; acc.y += v.y; acc.z += v.z; acc.w += v.w;
        }
    }

    float4* o = reinterpret_cast<float4*>(out + (size_t)node * FEAT_DIM) + lane;
    if (PASS == 0) {
        *o = acc;                          // partial sum (overwrites poison)
    } else {
        float4 p = *o;                     // partial from pass 0
        const float inv = 1.0f / (float)NUM_SAMPLE;
        *o = make_float4((p.x + acc.x) * inv,
                         (p.y + acc.y) * inv,
                         (p.z + acc.z) * inv,
                         (p.w + acc.w) * inv);
    }
}

extern "C" void kernel_launch(void* const* d_in, const int* in_sizes, int n_in,
                              void* d_out, int out_size, void* d_ws, size_t ws_size,
                              hipStream_t stream) {
    const float* feat = (const float*)d_in[0];
    const int*   idx  = (const int*)d_in[1];
    float*       out  = (float*)d_out;

    const int total_threads = N_NODES * 32;
    const int block = 256;
    const int grid  = (total_threads + block - 1) / block;  // 12500

    agg_pass<0><<<grid, block, 0, stream>>>(feat, idx, out);
    agg_pass<1><<<grid, block, 0, stream>>>(feat, idx, out);
}

// Round 4
// 189.072 us; speedup vs baseline: 1.3311x; 1.3311x over previous
//
#include <hip/hip_runtime.h>

#define N_NODES 100000
#define NUM_SAMPLE 25
#define FEAT_DIM 128

typedef float f32x4 __attribute__((ext_vector_type(4)));

// One 32-lane group per output node; lane l owns float4 chunk l of the row.
// idx row (25 ints) is fetched by lanes 0..24 in ONE coalesced load and
// broadcast via __shfl(width=32) -> all 25 gather addresses known up front,
// full unroll lets the scheduler keep many gathers in flight.
// idx loads and out stores are non-temporal (gfx950 `nt` bit) so they don't
// evict feature rows from L2/L3 -- the 256 MB table exactly fits L3.
__global__ __launch_bounds__(256) void MeanAggregator_kernel(
    const float* __restrict__ feat,
    const int* __restrict__ idx,
    float* __restrict__ out)
{
    const int gid  = blockIdx.x * blockDim.x + threadIdx.x;
    const int node = gid >> 5;           // 32 lanes per node
    const int lane = gid & 31;
    if (node >= N_NODES) return;

    // Coalesced idx fetch: lane s (s<25) holds idx[node][s].
    int my_idx = 0;
    if (lane < NUM_SAMPLE) {
        my_idx = __builtin_nontemporal_load(idx + node * NUM_SAMPLE + lane);
    }

    f32x4 acc = {0.f, 0.f, 0.f, 0.f};

    #pragma unroll
    for (int s = 0; s < NUM_SAMPLE; ++s) {
        const int r = __shfl(my_idx, s, 32);   // broadcast within the node group
        const f32x4 v = reinterpret_cast<const f32x4*>(
                            feat + (size_t)r * FEAT_DIM)[lane];
        acc += v;
    }

    const float inv = 1.0f / (float)NUM_SAMPLE;
    acc *= inv;
    __builtin_nontemporal_store(acc, reinterpret_cast<f32x4*>(
                                         out + (size_t)node * FEAT_DIM) + lane);
}

extern "C" void kernel_launch(void* const* d_in, const int* in_sizes, int n_in,
                              void* d_out, int out_size, void* d_ws, size_t ws_size,
                              hipStream_t stream) {
    const float* feat = (const float*)d_in[0];
    const int*   idx  = (const int*)d_in[1];
    float*       out  = (float*)d_out;

    const int total_threads = N_NODES * 32;
    const int block = 256;
    const int grid  = (total_threads + block - 1) / block;  // 12500

    MeanAggregator_kernel<<<grid, block, 0, stream>>>(feat, idx, out);
}

// Round 5
// 188.755 us; speedup vs baseline: 1.3333x; 1.0017x over previous
//
#include <hip/hip_runtime.h>

#define N_NODES 100000
#define NUM_SAMPLE 25
#define FEAT_DIM 128

typedef float f32x4 __attribute__((ext_vector_type(4)));

// One 32-lane group per output node; lane l owns float4 chunk l of the row.
// NEW vs round 4: each group bitonic-sorts its 25 indices ascending (lanes
// 25..31 hold INT_MAX sentinels, which sort to the top). All resident waves
// then traverse the vocab in the same ascending order, so at any instant the
// active feature working set is a narrow moving window (~10-30 MB) instead of
// the full random 256 MB -- concentrating repeats for L2/MALL and improving
// DRAM row locality. Sum order change is ~1e-6 fp32 noise.
__global__ __launch_bounds__(256) void MeanAggregator_kernel(
    const float* __restrict__ feat,
    const int* __restrict__ idx,
    float* __restrict__ out)
{
    const int gid  = blockIdx.x * blockDim.x + threadIdx.x;
    const int node = gid >> 5;           // 32 lanes per node
    const int lane = gid & 31;
    if (node >= N_NODES) return;

    // Coalesced idx fetch: lane s (s<25) holds idx[node][s]; sentinel elsewhere.
    int v = 0x7fffffff;
    if (lane < NUM_SAMPLE) {
        v = __builtin_nontemporal_load(idx + node * NUM_SAMPLE + lane);
    }

    // 32-lane bitonic sort, ascending. 15 compare-exchange stages, VALU-only
    // (VALU is ~94% idle in this kernel -- effectively free).
    #pragma unroll
    for (int k = 2; k <= 32; k <<= 1) {
        #pragma unroll
        for (int j = k >> 1; j >= 1; j >>= 1) {
            const int p = __shfl_xor(v, j, 32);
            const bool up      = ((lane & k) == 0);   // ascending block?
            const bool lower   = ((lane & j) == 0);   // lower element of pair?
            const bool keepMin = (lower == up);
            v = keepMin ? min(v, p) : max(v, p);
        }
    }
    // lanes 0..24 now hold the 25 real indices in ascending order.

    f32x4 acc = {0.f, 0.f, 0.f, 0.f};

    #pragma unroll
    for (int s = 0; s < NUM_SAMPLE; ++s) {
        const int r = __shfl(v, s, 32);   // broadcast s-th smallest index
        acc += reinterpret_cast<const f32x4*>(feat + (size_t)r * FEAT_DIM)[lane];
    }

    const float inv = 1.0f / (float)NUM_SAMPLE;
    acc *= inv;
    __builtin_nontemporal_store(acc, reinterpret_cast<f32x4*>(
                                         out + (size_t)node * FEAT_DIM) + lane);
}

extern "C" void kernel_launch(void* const* d_in, const int* in_sizes, int n_in,
                              void* d_out, int out_size, void* d_ws, size_t ws_size,
                              hipStream_t stream) {
    const float* feat = (const float*)d_in[0];
    const int*   idx  = (const int*)d_in[1];
    float*       out  = (float*)d_out;

    const int total_threads = N_NODES * 32;
    const int block = 256;
    const int grid  = (total_threads + block - 1) / block;  // 12500

    MeanAggregator_kernel<<<grid, block, 0, stream>>>(feat, idx, out);
}